// Round 1
// baseline (107.126 us; speedup 1.0000x reference)
//
#include <hip/hip_runtime.h>
#include <stdint.h>

constexpr int KD = 10000;       // hypervector dim
constexpr int KP = 784;         // pixel positions
constexpr int KB = 16;          // batch
constexpr int KL = 256;         // levels
constexpr int KROWS = KP + KL;  // 1040 rows to pack
constexpr int KCHUNK = 157;     // ceil(10000 / 64) 64-bit ballot chunks per row

// Workspace (layout unchanged from previous version):
//   posb uint32[80 wg][784 p][4 w]  @ 0          = 1,003,520 B
//   valb uint32[80 wg][256 l][4 w]  @ 1,003,520  =   327,680 B
// Tiled layout => accum loads are contiguous 16B per (p,wg) pair.

// One row per 256-thread block (4 waves). Lane i loads float d = c*64+i
// (perfectly coalesced dword loads), sign bit -> __ballot -> 64 packed bits
// per wave-op. Wave `sub` handles chunks [sub*40, min(sub*40+40, 157)).
__global__ __launch_bounds__(256) void pack_kernel(const float* __restrict__ pos,
                                                   const float* __restrict__ val,
                                                   uint32_t* __restrict__ posb,
                                                   uint32_t* __restrict__ valb) {
    int r    = blockIdx.x;      // 0..1039
    int t    = threadIdx.x;     // 0..255
    int lane = t & 63;
    int sub  = t >> 6;          // wave 0..3

    const float* src;
    uint32_t* dst;
    int rr, rowstride;
    if (r < KP) { src = pos; dst = posb; rr = r;      rowstride = KP; }
    else        { src = val; dst = valb; rr = r - KP; rowstride = KL; }
    const float* srow = src + (size_t)rr * KD;

    int cbeg = sub * 40;
    int cend = min(cbeg + 40, KCHUNK);
    #pragma unroll 4
    for (int c = cbeg; c < cend; ++c) {
        int d = c * 64 + lane;
        uint32_t sgn = 0;
        if (d < KD) sgn = __float_as_uint(srow[d]) >> 31;   // +-1.0 -> sign bit
        unsigned long long m = __ballot(sgn != 0);
        if (lane < 2) {                                     // bit `lane` of m == d = c*64+lane
            int W = 2 * c + lane;                           // word covers d = 32W..32W+31
            uint32_t word = (uint32_t)(m >> (32 * lane));
            dst[((size_t)(W >> 2) * rowstride + rr) * 4 + (W & 3)] = word;
        }
    }
    // zero padding words W = 314..319 (W=312 top bits and W=313 are zeroed by
    // the masked ballot in chunk 156; workspace is poisoned so these must be
    // written explicitly)
    if (sub == 3 && lane < 6) {
        int W = 314 + lane;
        dst[((size_t)(W >> 2) * rowstride + rr) * 4 + (W & 3)] = 0u;
    }
}

// One 256-thread block (4 waves) per (word-group, batch). Thread
// (w = t&3, g = (t>>2)&15, sub = t>>6): wave `sub` handles i = sub + 4*ii
// (13 iters for sub 0, 12 for sub 1..3) -> CSA 4-bit vertical counters,
// SWAR byte extraction, LDS reduce over 4 subs x 16 p-subgroups, sign -> out.
__global__ __launch_bounds__(256) void accum_kernel(const uint32_t* __restrict__ posb,
                                                    const uint32_t* __restrict__ valb,
                                                    const float* __restrict__ x,
                                                    float* __restrict__ out) {
    __shared__ int sidx[KP];              // level * 16 (byte offset into wg slice)
    __shared__ uint32_t red[4][8][16][5]; // [sub][k][g][w] (+1 pad on w)
    int wg = blockIdx.x;   // 0..78 (wg 79 is pure padding, not launched)
    int b  = blockIdx.y;   // 0..15
    int t  = threadIdx.x;  // 0..255

    for (int p = t; p < KP; p += 256) {
        float v = x[b * KP + p] * 255.0f;
        float r = fminf(fmaxf(rintf(v), 0.0f), 255.0f);   // round-half-even = jnp.round
        sidx[p] = (int)r * 16;
    }
    __syncthreads();

    int w = t & 3, g = (t >> 2) & 15, sub = t >> 6;
    const uint32_t* pb = posb + (size_t)wg * KP * 4 + w;
    const char*     vb = (const char*)(valb + (size_t)wg * KL * 4 + w);
    uint32_t c0 = 0, c1 = 0, c2 = 0, c3 = 0;
    #pragma unroll
    for (int ii = 0; ii < 13; ++ii) {
        int i = sub + ii * 4;                             // wave-uniform split of 0..48
        if (i < 49) {                                     // only sub==0 runs ii==12
            int p = i * 16 + g;                           // 64 consecutive words per wave
            uint32_t xp = pb[p * 4];
            uint32_t xv = *(const uint32_t*)(vb + sidx[p]);
            uint32_t carry = xp ^ xv, tt;                 // 1 = negative product
            tt = c0 & carry; c0 ^= carry; carry = tt;
            tt = c1 & carry; c1 ^= carry; carry = tt;
            tt = c2 & carry; c2 ^= carry; carry = tt;
            c3 ^= carry;                                  // max 13 < 16
        }
    }
    // byte-packed extraction: vk byte B = count for d_local = k + 8*B (<= 13, no carry)
    #pragma unroll
    for (int k = 0; k < 8; ++k) {
        uint32_t vk = ((c0 >> k) & 0x01010101u)
                    | (((c1 >> k) & 0x01010101u) << 1)
                    | (((c2 >> k) & 0x01010101u) << 2)
                    | (((c3 >> k) & 0x01010101u) << 3);
        red[sub][k][g][w] = vk;
    }
    __syncthreads();

    if (t < 32) {
        int rw = t & 3, rk = t >> 2;
        uint32_t lo = 0, hi = 0;
        #pragma unroll
        for (int ss = 0; ss < 4; ++ss) {
            #pragma unroll
            for (int gg = 0; gg < 16; ++gg) {             // 16-bit lane sums <= 784
                uint32_t v = red[ss][rk][gg][rw];
                lo += v & 0x00FF00FFu;
                hi += (v >> 8) & 0x00FF00FFu;
            }
        }
        int c_0  = (int)(lo & 0xFFFFu);                   // d_local = rk
        int c_16 = (int)(lo >> 16);                       // d_local = rk+16
        int c_8  = (int)(hi & 0xFFFFu);                   // d_local = rk+8
        int c_24 = (int)(hi >> 16);                       // d_local = rk+24
        int dbase = wg * 128 + rw * 32 + rk;
        float* ob = out + (size_t)b * KD;
        // s = 784 - 2*count > 0  <=>  count < 392  (count == 392 -> s == 0 -> -1)
        if (dbase      < KD) ob[dbase]      = (c_0  < 392) ? 1.0f : -1.0f;
        if (dbase + 8  < KD) ob[dbase + 8]  = (c_8  < 392) ? 1.0f : -1.0f;
        if (dbase + 16 < KD) ob[dbase + 16] = (c_16 < 392) ? 1.0f : -1.0f;
        if (dbase + 24 < KD) ob[dbase + 24] = (c_24 < 392) ? 1.0f : -1.0f;
    }
}

extern "C" void kernel_launch(void* const* d_in, const int* in_sizes, int n_in,
                              void* d_out, int out_size, void* d_ws, size_t ws_size,
                              hipStream_t stream) {
    const float* x   = (const float*)d_in[0];
    const float* pos = (const float*)d_in[1];
    const float* val = (const float*)d_in[2];
    float* out = (float*)d_out;

    char* ws = (char*)d_ws;
    uint32_t* posb = (uint32_t*)ws;
    uint32_t* valb = (uint32_t*)(ws + (size_t)80 * KP * 4 * sizeof(uint32_t)); // 1,003,520

    pack_kernel<<<KROWS, 256, 0, stream>>>(pos, val, posb, valb);
    accum_kernel<<<dim3(79, KB), 256, 0, stream>>>(posb, valb, x, out);
}

// Round 2
// 91.123 us; speedup vs baseline: 1.1756x; 1.1756x over previous
//
#include <hip/hip_runtime.h>
#include <stdint.h>

constexpr int KD = 10000;       // hypervector dim
constexpr int KP = 784;         // pixel positions
constexpr int KB = 16;          // batch
constexpr int KL = 256;         // levels
constexpr int KW = 320;         // padded uint32 words per row (10240 bits >= 10000)
constexpr int KNWG = 80;        // word-groups of 4 words (128 d's each)
constexpr int KROWS = KP + KL;  // 1040 rows to pack

// Workspace:
//   posb uint32[80 wg][784 p][4 w]  @ 0          = 1,003,520 B
//   valb uint32[80 wg][256 l][4 w]  @ 1,003,520  =   327,680 B
// Tiled layout => accum loads are contiguous 16B per (p,wg) pair.

// Round-0 proven pack: one word (32 d's) per thread, 8x float4 = 128B
// contiguous per thread. The 8-deep unroll re-hits the same 64 L1 lines
// while resident -> effective traffic ~= ideal 42MB (~10us).
__global__ __launch_bounds__(256) void pack_kernel(const float* __restrict__ pos,
                                                   const float* __restrict__ val,
                                                   uint32_t* __restrict__ posb,
                                                   uint32_t* __restrict__ valb) {
    int tid = blockIdx.x * 256 + threadIdx.x;   // 332,800 = 1040 rows * 320 words exact
    int r = tid / KW;
    int W = tid - r * KW;
    const float* src = (r < KP) ? pos : val;
    int rr = (r < KP) ? r : r - KP;
    uint32_t word = 0;
    const float4* s4 = (const float4*)(src + (size_t)rr * KD + W * 32);
    if (W < 312) {
        #pragma unroll
        for (int j = 0; j < 8; ++j) {
            float4 f = s4[j];
            uint32_t s = (__float_as_uint(f.x) >> 31)
                       | ((__float_as_uint(f.y) >> 31) << 1)
                       | ((__float_as_uint(f.z) >> 31) << 2)
                       | ((__float_as_uint(f.w) >> 31) << 3);
            word |= s << (4 * j);
        }
    } else if (W == 312) {      // d 9984..9999: exactly 4 float4s, upper 16 bits = 0
        #pragma unroll
        for (int j = 0; j < 4; ++j) {
            float4 f = s4[j];
            uint32_t s = (__float_as_uint(f.x) >> 31)
                       | ((__float_as_uint(f.y) >> 31) << 1)
                       | ((__float_as_uint(f.z) >> 31) << 2)
                       | ((__float_as_uint(f.w) >> 31) << 3);
            word |= s << (4 * j);
        }
    }                           // W in 313..319: zero padding
    int wg = W >> 2, w = W & 3;
    if (r < KP) posb[((size_t)wg * KP + rr) * 4 + w] = word;
    else        valb[((size_t)wg * KL + rr) * 4 + w] = word;
}

// One 256-thread block (4 waves) per (word-group, batch). Thread
// (w = t&3, g = (t>>2)&15, sub = t>>6). Wave `sub` takes a CONTIGUOUS
// i-range (13/12/12/12 of the 49 p-supergroups) -> runtime trip count,
// partial unroll, no per-iteration guard (the round-1 full-unroll+guard
// variant is the suspected codegen regression). Per (wave, iter) the posb
// read is still 64 consecutive words = 256B coalesced; 4 waves/block
// lifts TLP ~1.25 -> ~5 waves/SIMD to hide the sidx(LDS)->valb(L2) chain.
__global__ __launch_bounds__(256) void accum_kernel(const uint32_t* __restrict__ posb,
                                                    const uint32_t* __restrict__ valb,
                                                    const float* __restrict__ x,
                                                    float* __restrict__ out) {
    __shared__ int sidx[KP];              // level * 16 (byte offset into wg slice)
    __shared__ uint32_t red[4][8][16][5]; // [sub][k][g][w] (+1 pad on w)
    int wg = blockIdx.x;   // 0..78 (wg 79 is pure padding, not launched)
    int b  = blockIdx.y;   // 0..15
    int t  = threadIdx.x;  // 0..255

    for (int p = t; p < KP; p += 256) {
        float v = x[b * KP + p] * 255.0f;
        float r = fminf(fmaxf(rintf(v), 0.0f), 255.0f);   // round-half-even = jnp.round
        sidx[p] = (int)r * 16;
    }
    __syncthreads();

    int w = t & 3, g = (t >> 2) & 15, sub = t >> 6;
    const uint32_t* pb = posb + (size_t)wg * KP * 4 + w;
    const char*     vb = (const char*)(valb + (size_t)wg * KL * 4 + w);
    int ibeg = (sub == 0) ? 0 : 13 + (sub - 1) * 12;      // 0,13,25,37
    int iend = (sub == 0) ? 13 : ibeg + 12;               // 13,25,37,49
    uint32_t c0 = 0, c1 = 0, c2 = 0, c3 = 0;
    #pragma unroll 6
    for (int i = ibeg; i < iend; ++i) {
        int p = i * 16 + g;                               // 64 consecutive words per wave
        uint32_t xp = pb[p * 4];
        uint32_t xv = *(const uint32_t*)(vb + sidx[p]);
        uint32_t carry = xp ^ xv, tt;                     // 1 = negative product
        tt = c0 & carry; c0 ^= carry; carry = tt;
        tt = c1 & carry; c1 ^= carry; carry = tt;
        tt = c2 & carry; c2 ^= carry; carry = tt;
        c3 ^= carry;                                      // max 13 < 16
    }
    // byte-packed extraction: vk byte B = count for d_local = k + 8*B (<= 13, no carry)
    #pragma unroll
    for (int k = 0; k < 8; ++k) {
        uint32_t vk = ((c0 >> k) & 0x01010101u)
                    | (((c1 >> k) & 0x01010101u) << 1)
                    | (((c2 >> k) & 0x01010101u) << 2)
                    | (((c3 >> k) & 0x01010101u) << 3);
        red[sub][k][g][w] = vk;
    }
    __syncthreads();

    if (t < 32) {
        int rw = t & 3, rk = t >> 2;
        uint32_t lo = 0, hi = 0;
        #pragma unroll
        for (int ss = 0; ss < 4; ++ss) {
            #pragma unroll
            for (int gg = 0; gg < 16; ++gg) {             // 16-bit lane sums <= 784
                uint32_t v = red[ss][rk][gg][rw];
                lo += v & 0x00FF00FFu;
                hi += (v >> 8) & 0x00FF00FFu;
            }
        }
        int c_0  = (int)(lo & 0xFFFFu);                   // d_local = rk
        int c_16 = (int)(lo >> 16);                       // d_local = rk+16
        int c_8  = (int)(hi & 0xFFFFu);                   // d_local = rk+8
        int c_24 = (int)(hi >> 16);                       // d_local = rk+24
        int dbase = wg * 128 + rw * 32 + rk;
        float* ob = out + (size_t)b * KD;
        // s = 784 - 2*count > 0  <=>  count < 392  (count == 392 -> s == 0 -> -1)
        if (dbase      < KD) ob[dbase]      = (c_0  < 392) ? 1.0f : -1.0f;
        if (dbase + 8  < KD) ob[dbase + 8]  = (c_8  < 392) ? 1.0f : -1.0f;
        if (dbase + 16 < KD) ob[dbase + 16] = (c_16 < 392) ? 1.0f : -1.0f;
        if (dbase + 24 < KD) ob[dbase + 24] = (c_24 < 392) ? 1.0f : -1.0f;
    }
}

extern "C" void kernel_launch(void* const* d_in, const int* in_sizes, int n_in,
                              void* d_out, int out_size, void* d_ws, size_t ws_size,
                              hipStream_t stream) {
    const float* x   = (const float*)d_in[0];
    const float* pos = (const float*)d_in[1];
    const float* val = (const float*)d_in[2];
    float* out = (float*)d_out;

    char* ws = (char*)d_ws;
    uint32_t* posb = (uint32_t*)ws;
    uint32_t* valb = (uint32_t*)(ws + (size_t)KNWG * KP * 4 * sizeof(uint32_t)); // 1,003,520

    pack_kernel<<<1300, 256, 0, stream>>>(pos, val, posb, valb);
    accum_kernel<<<dim3(79, KB), 256, 0, stream>>>(posb, valb, x, out);
}